// Round 6
// baseline (386.188 us; speedup 1.0000x reference)
//
#include <hip/hip_runtime.h>

typedef short short8 __attribute__((ext_vector_type(8)));
typedef float f32x4 __attribute__((ext_vector_type(4)));

#define H 128
#define NB 4            // real batch rows per block
#define TSTEPS 64
#define PRED 32
#define XSTRIDE 260

// MFMA D rows are l4*4+reg; reg 0 rows {0,4,8,12} are the real rows; real
// batch row = l4. Garbage LDS h-rows are zeroed once and never rewritten, so
// they stay finite forever; garbage D rows get acc=bias only (never stored).
// Real-row arithmetic is bit-identical to the R2/R4/R5 verified datapath.

static __device__ __forceinline__ unsigned short bf16_rne(float f) {
  unsigned u = __builtin_bit_cast(unsigned, f);
  u += 0x7fffu + ((u >> 16) & 1u);
  return (unsigned short)(u >> 16);
}
static __device__ __forceinline__ float bf16_f(unsigned short s) {
  unsigned u = ((unsigned)s) << 16;
  return __builtin_bit_cast(float, u);
}
// R2's tanh (verified 4.88e-4 end-to-end). Do NOT swap for raw v_exp/v_rcp —
// that variant cost 43x accuracy over the 96-step recurrence (R3 post-mortem:
// biased per-step error compounds coherently through the recurrence).
static __device__ __forceinline__ float tanh_fast(float v) {
  v = fminf(9.0f, fmaxf(-9.0f, v));
  float e = __expf(2.0f * v);
  return __fdividef(e - 1.0f, e + 1.0f);
}

static __device__ __forceinline__ void split_frag(const f32x4& a, const f32x4& b,
                                                  short8& hi, short8& lo) {
  #pragma unroll
  for (int e = 0; e < 4; ++e) {
    unsigned short h1 = bf16_rne(a[e]);
    hi[e] = (short)h1;
    lo[e] = (short)bf16_rne(a[e] - bf16_f(h1));
    unsigned short h2 = bf16_rne(b[e]);
    hi[e + 4] = (short)h2;
    lo[e + 4] = (short)bf16_rne(b[e] - bf16_f(h2));
  }
}

__global__ __launch_bounds__(512, 8) void traj_kernel(
    const float* __restrict__ x,
    const float* __restrict__ eWih, const float* __restrict__ eWhh,
    const float* __restrict__ ebih, const float* __restrict__ ebhh,
    const float* __restrict__ dWih, const float* __restrict__ dWhh,
    const float* __restrict__ dbih, const float* __restrict__ dbhh,
    const float* __restrict__ fcW, const float* __restrict__ fcb,
    float* __restrict__ out)
{
  __shared__ __align__(16) float x_lds[NB * XSTRIDE];       // 4.2 KB
  __shared__ __align__(16) short h_hi0[16 * H], h_lo0[16 * H];
  __shared__ __align__(16) short h_hi1[16 * H], h_lo1[16 * H];  // 16 KB total
  __shared__ float inp_lds[NB][4];

  const int tid = threadIdx.x;
  const int lane = tid & 63;
  const int w = tid >> 6;
  const int l4 = lane >> 4;
  const int ln = lane & 15;
  const int r0 = blockIdx.x * NB;
  const int jj = w * 16 + ln;

  // ---- stage x: 4 real rows (768 contiguous floats) into padded LDS ----
  {
    int flat = tid;
    if (flat < 768) {
      int r = flat / 192, rem = flat - r * 192;
      int t = rem / 3, i = rem - t * 3;
      x_lds[r * XSTRIDE + t * 4 + i] = x[(size_t)r0 * 192 + flat];
    }
    flat = tid + 512;
    if (flat < 768) {
      int r = flat / 192, rem = flat - r * 192;
      int t = rem / 3, i = rem - t * 3;
      x_lds[r * XSTRIDE + t * 4 + i] = x[(size_t)r0 * 192 + flat];
    }
  }
  // ---- zero both h buffers (garbage rows must stay finite forever) ----
  #pragma unroll
  for (int s = 0; s < 4; ++s) {
    h_hi0[tid + s * 512] = 0; h_hi1[tid + s * 512] = 0;
    h_lo0[tid + s * 512] = 0; h_lo1[tid + s * 512] = 0;
  }

  // ---- encoder weights (row jj of eWhh), split hi/lo ----
  short8 whi[4], wlo[4];
  #pragma unroll
  for (int kt = 0; kt < 4; ++kt) {
    const float* p = eWhh + jj * H + kt * 32 + l4 * 8;
    split_frag(*(const f32x4*)p, *(const f32x4*)(p + 4), whi[kt], wlo[kt]);
  }
  float bias = ebih[jj] + ebhh[jj];
  float wi[3];
  #pragma unroll
  for (int i = 0; i < 3; ++i) wi[i] = eWih[jj * 3 + i];

  // ---- loop-invariant LDS offsets ----
  int roff[4];
  #pragma unroll
  for (int kt = 0; kt < 4; ++kt)
    roff[kt] = ln * H + ((((kt << 2) + l4) ^ ln) << 3);
  const int rr = l4 * 4;                       // real MFMA/LDS row
  const int wo = rr * H + (((jj >> 3) ^ rr) << 3) + (jj & 7);
  const int xb = l4 * XSTRIDE;                 // x row = batch row l4

  auto load_frags = [&](const short* __restrict__ hh, const short* __restrict__ hl,
                        short8* ah, short8* al) {
    #pragma unroll
    for (int kt = 0; kt < 4; ++kt) {
      ah[kt] = *(const short8*)&hh[roff[kt]];
      al[kt] = *(const short8*)&hl[roff[kt]];
    }
  };
  auto rnn_core = [&](const short8* ah, const short8* al, f32x4 acc0,
                      short* __restrict__ wh, short* __restrict__ wl) {
    f32x4 accb = {0.f, 0.f, 0.f, 0.f};
    f32x4 accc = {0.f, 0.f, 0.f, 0.f};
    #pragma unroll
    for (int kt = 0; kt < 4; ++kt) {   // 3 independent 4-deep MFMA chains
      acc0 = __builtin_amdgcn_mfma_f32_16x16x32_bf16(ah[kt], whi[kt], acc0, 0, 0, 0);
      accb = __builtin_amdgcn_mfma_f32_16x16x32_bf16(ah[kt], wlo[kt], accb, 0, 0, 0);
      accc = __builtin_amdgcn_mfma_f32_16x16x32_bf16(al[kt], whi[kt], accc, 0, 0, 0);
    }
    float v = tanh_fast(acc0[0] + accb[0] + accc[0]);   // reg 0 = real row
    unsigned short p = bf16_rne(v);
    wh[wo] = (short)p;
    wl[wo] = (short)bf16_rne(v - bf16_f(p));
  };

  __syncthreads();

  // ======================= encoder: 64 steps, unrolled x2 =======================
  for (int t = 0; t < TSTEPS; t += 2) {
    {
      short8 ah[4], al[4];
      load_frags(h_hi0, h_lo0, ah, al);
      const f32x4 xv = *(const f32x4*)&x_lds[xb + t * 4];
      f32x4 a = {bias + wi[0] * xv[0] + wi[1] * xv[1] + wi[2] * xv[2],
                 bias, bias, bias};
      rnn_core(ah, al, a, h_hi1, h_lo1);
    }
    __syncthreads();
    {
      short8 ah[4], al[4];
      load_frags(h_hi1, h_lo1, ah, al);
      const f32x4 xv = *(const f32x4*)&x_lds[xb + (t + 1) * 4];
      f32x4 a = {bias + wi[0] * xv[0] + wi[1] * xv[1] + wi[2] * xv[2],
                 bias, bias, bias};
      rnn_core(ah, al, a, h_hi0, h_lo0);
    }
    __syncthreads();
  }
  // h_enc now in h_hi0/h_lo0.

  // ======================= decoder setup =======================
  #pragma unroll
  for (int kt = 0; kt < 4; ++kt) {
    const float* p = dWhh + jj * H + kt * 32 + l4 * 8;
    split_frag(*(const f32x4*)p, *(const f32x4*)(p + 4), whi[kt], wlo[kt]);
  }
  bias = dbih[jj] + dbhh[jj];
  #pragma unroll
  for (int i = 0; i < 3; ++i) wi[i] = dWih[jj * 3 + i];

  // fc head as MFMA B-fragments: B[k][n=o] = fcW[o][k], lanes ln>=3 zero.
  short8 fhi[4];
  #pragma unroll
  for (int kt = 0; kt < 4; ++kt) {
    f32x4 a = {0.f, 0.f, 0.f, 0.f}, b = {0.f, 0.f, 0.f, 0.f};
    if (ln < 3) {
      const float* p = fcW + ln * H + kt * 32 + l4 * 8;
      a = *(const f32x4*)p;
      b = *(const f32x4*)(p + 4);
    }
    short8 hi;
    #pragma unroll
    for (int e = 0; e < 4; ++e) {
      hi[e] = (short)bf16_rne(a[e]);
      hi[e + 4] = (short)bf16_rne(b[e]);
    }
    fhi[kt] = hi;
  }
  const float fcbl = (ln < 3) ? fcb[ln] : 0.f;

  if (tid < 12) {
    int r = tid / 3, i = tid - 3 * (tid / 3);
    inp_lds[r][i] = x_lds[r * XSTRIDE + 63 * 4 + i];   // dec_in0 = x[:, -1, :]
  }
  __syncthreads();

  // ---- decoder step 0 (raw dWhh + real input) ----
  {
    short8 ah[4], al[4];
    load_frags(h_hi0, h_lo0, ah, al);
    f32x4 a = {bias + wi[0] * inp_lds[l4][0] + wi[1] * inp_lds[l4][1]
                    + wi[2] * inp_lds[l4][2],
               bias, bias, bias};
    rnn_core(ah, al, a, h_hi1, h_lo1);
  }
  __syncthreads();

  // ---- fold feedback: W' = dWhh + dWih@fcW ; bias' = bias + dWih@fcb ----
  #pragma unroll
  for (int kt = 0; kt < 4; ++kt) {
    const int kb = kt * 32 + l4 * 8;
    f32x4 a = *(const f32x4*)(dWhh + jj * H + kb);
    f32x4 b = *(const f32x4*)(dWhh + jj * H + kb + 4);
    #pragma unroll
    for (int o = 0; o < 3; ++o) {
      const f32x4 fa = *(const f32x4*)(fcW + o * H + kb);
      const f32x4 fb = *(const f32x4*)(fcW + o * H + kb + 4);
      #pragma unroll
      for (int e = 0; e < 4; ++e) {
        a[e] += wi[o] * fa[e];
        b[e] += wi[o] * fb[e];
      }
    }
    split_frag(a, b, whi[kt], wlo[kt]);
  }
  const float biasp = bias + wi[0] * fcb[0] + wi[1] * fcb[1] + wi[2] * fcb[2];
  const f32x4 accd = {biasp, biasp, biasp, biasp};

  // ======================= decoder steps 1..31: 1 barrier/step =======================
  const short* rdh = h_hi1; const short* rdl = h_lo1;
  short* wrh = h_hi0;       short* wrl = h_lo0;
  for (int s = 1; s < PRED; ++s) {
    short8 ah[4], al[4];
    load_frags(rdh, rdl, ah, al);
    rnn_core(ah, al, accd, wrh, wrl);
    // pred[s-1] = fcW·h[s-1] + fcb via MFMA on one rotating wave (off-path)
    if (w == (s & 7)) {
      f32x4 f0 = {0.f, 0.f, 0.f, 0.f};
      f32x4 f1 = {0.f, 0.f, 0.f, 0.f};
      #pragma unroll
      for (int kt = 0; kt < 4; ++kt) {
        f0 = __builtin_amdgcn_mfma_f32_16x16x32_bf16(ah[kt], fhi[kt], f0, 0, 0, 0);
        f1 = __builtin_amdgcn_mfma_f32_16x16x32_bf16(al[kt], fhi[kt], f1, 0, 0, 0);
      }
      if (ln < 3)
        out[((size_t)(r0 + l4) * PRED + (s - 1)) * 3 + ln] = f0[0] + f1[0] + fcbl;
    }
    __syncthreads();
    const short* th = rdh; rdh = wrh; wrh = (short*)th;
    const short* tl = rdl; rdl = wrl; wrl = (short*)tl;
  }
  // ---- drain: pred[31] from final h ----
  if (w == 0) {
    short8 ah[4], al[4];
    load_frags(rdh, rdl, ah, al);
    f32x4 f0 = {0.f, 0.f, 0.f, 0.f};
    f32x4 f1 = {0.f, 0.f, 0.f, 0.f};
    #pragma unroll
    for (int kt = 0; kt < 4; ++kt) {
      f0 = __builtin_amdgcn_mfma_f32_16x16x32_bf16(ah[kt], fhi[kt], f0, 0, 0, 0);
      f1 = __builtin_amdgcn_mfma_f32_16x16x32_bf16(al[kt], fhi[kt], f1, 0, 0, 0);
    }
    if (ln < 3)
      out[((size_t)(r0 + l4) * PRED + (PRED - 1)) * 3 + ln] = f0[0] + f1[0] + fcbl;
  }
}

extern "C" void kernel_launch(void* const* d_in, const int* in_sizes, int n_in,
                              void* d_out, int out_size, void* d_ws, size_t ws_size,
                              hipStream_t stream) {
  (void)in_sizes; (void)n_in; (void)out_size; (void)d_ws; (void)ws_size;
  const float* x    = (const float*)d_in[0];
  const float* eWih = (const float*)d_in[1];
  const float* eWhh = (const float*)d_in[2];
  const float* ebih = (const float*)d_in[3];
  const float* ebhh = (const float*)d_in[4];
  const float* dWih = (const float*)d_in[5];
  const float* dWhh = (const float*)d_in[6];
  const float* dbih = (const float*)d_in[7];
  const float* dbhh = (const float*)d_in[8];
  const float* fcW  = (const float*)d_in[9];
  const float* fcb  = (const float*)d_in[10];
  float* out = (float*)d_out;
  traj_kernel<<<dim3(1024), dim3(512), 0, stream>>>(
      x, eWih, eWhh, ebih, ebhh, dWih, dWhh, dbih, dbhh, fcW, fcb, out);
}

// Round 7
// 151.386 us; speedup vs baseline: 2.5510x; 2.5510x over previous
//
#include <hip/hip_runtime.h>

typedef short short8 __attribute__((ext_vector_type(8)));
typedef float f32x4 __attribute__((ext_vector_type(4)));

#define H 128
#define NB 16           // real batch rows per block — NO duplication
#define TSTEPS 64
#define PRED 32
#define XSTRIDE 260

// R7 geometry: 256 blocks x 512 thr (8 waves), 1 block/CU. Each wave: 16 real
// rows x 16 cols (jj = w*16+ln). Instruction-minimal point: 64 LDS reads +
// 96 MFMA per CU-step (vs R5's 128+192 with 2x row-duplication).
// R6 lesson: do NOT demand occupancy beyond the register footprint —
// bounds(512,8) forced 64-VGPR target -> scratch spills -> 259MB writes.

static __device__ __forceinline__ unsigned short bf16_rne(float f) {
  unsigned u = __builtin_bit_cast(unsigned, f);
  u += 0x7fffu + ((u >> 16) & 1u);
  return (unsigned short)(u >> 16);
}
static __device__ __forceinline__ float bf16_f(unsigned short s) {
  unsigned u = ((unsigned)s) << 16;
  return __builtin_bit_cast(float, u);
}
// R2's tanh (verified 4.88e-4 end-to-end). Do NOT swap for raw v_exp/v_rcp —
// that variant cost 43x accuracy over the 96-step recurrence (R3 post-mortem:
// per-step error is amplified ~60-100x through the recurrence).
static __device__ __forceinline__ float tanh_fast(float v) {
  v = fminf(9.0f, fmaxf(-9.0f, v));
  float e = __expf(2.0f * v);
  return __fdividef(e - 1.0f, e + 1.0f);
}

static __device__ __forceinline__ void split_frag(const f32x4& a, const f32x4& b,
                                                  short8& hi, short8& lo) {
  #pragma unroll
  for (int e = 0; e < 4; ++e) {
    unsigned short h1 = bf16_rne(a[e]);
    hi[e] = (short)h1;
    lo[e] = (short)bf16_rne(a[e] - bf16_f(h1));
    unsigned short h2 = bf16_rne(b[e]);
    hi[e + 4] = (short)h2;
    lo[e + 4] = (short)bf16_rne(b[e] - bf16_f(h2));
  }
}

__global__ __launch_bounds__(512, 2) void traj_kernel(
    const float* __restrict__ x,
    const float* __restrict__ eWih, const float* __restrict__ eWhh,
    const float* __restrict__ ebih, const float* __restrict__ ebhh,
    const float* __restrict__ dWih, const float* __restrict__ dWhh,
    const float* __restrict__ dbih, const float* __restrict__ dbhh,
    const float* __restrict__ fcW, const float* __restrict__ fcb,
    float* __restrict__ out)
{
  __shared__ __align__(16) float x_lds[NB * XSTRIDE];          // 16.6 KB
  __shared__ __align__(16) short h_hi0[NB * H], h_lo0[NB * H];
  __shared__ __align__(16) short h_hi1[NB * H], h_lo1[NB * H]; // 16 KB
  __shared__ float inp_lds[NB][4];

  const int tid = threadIdx.x;
  const int lane = tid & 63;
  const int w = tid >> 6;          // wave 0..7 -> 16-col tile
  const int l4 = lane >> 4;
  const int ln = lane & 15;
  const int r0 = blockIdx.x * NB;
  const int jj = w * 16 + ln;      // this lane's hidden column

  // ---- stage x: 16 rows x 192 floats, contiguous ----
  #pragma unroll
  for (int s = 0; s < 6; ++s) {
    int flat = tid + s * 512;      // = r*192 + rem
    int r = flat / 192;
    int rem = flat - r * 192;
    int t = rem / 3;
    int i = rem - t * 3;
    x_lds[r * XSTRIDE + t * 4 + i] = x[(size_t)r0 * 192 + flat];
  }
  // ---- zero h buffer 0 (h0 = 0) ----
  #pragma unroll
  for (int s = 0; s < 4; ++s) {
    h_hi0[tid + s * 512] = 0;
    h_lo0[tid + s * 512] = 0;
  }

  // ---- encoder weights (row jj of eWhh), split hi/lo ----
  short8 whi[4], wlo[4];
  #pragma unroll
  for (int kt = 0; kt < 4; ++kt) {
    const float* p = eWhh + jj * H + kt * 32 + l4 * 8;
    split_frag(*(const f32x4*)p, *(const f32x4*)(p + 4), whi[kt], wlo[kt]);
  }
  float bias = ebih[jj] + ebhh[jj];
  float wi[3];
  #pragma unroll
  for (int i = 0; i < 3; ++i) wi[i] = eWih[jj * 3 + i];

  // ---- loop-invariant LDS offsets ----
  int roff[4];
  #pragma unroll
  for (int kt = 0; kt < 4; ++kt)
    roff[kt] = ln * H + ((((kt << 2) + l4) ^ ln) << 3);   // swizzled A-frag
  int wo[4], xb[4];
  #pragma unroll
  for (int reg = 0; reg < 4; ++reg) {
    const int r = l4 * 4 + reg;
    wo[reg] = r * H + (((jj >> 3) ^ r) << 3) + (jj & 7);  // swizzled write
    xb[reg] = r * XSTRIDE;
  }

  auto load_frags = [&](const short* __restrict__ hh, const short* __restrict__ hl,
                        short8* ah, short8* al) {
    #pragma unroll
    for (int kt = 0; kt < 4; ++kt) {
      ah[kt] = *(const short8*)&hh[roff[kt]];
      al[kt] = *(const short8*)&hl[roff[kt]];
    }
  };
  auto rnn_core = [&](const short8* ah, const short8* al, f32x4 acc0,
                      short* __restrict__ wh, short* __restrict__ wl) {
    f32x4 accb = {0.f, 0.f, 0.f, 0.f};
    f32x4 accc = {0.f, 0.f, 0.f, 0.f};
    #pragma unroll
    for (int kt = 0; kt < 4; ++kt) {   // 3 independent 4-deep MFMA chains
      acc0 = __builtin_amdgcn_mfma_f32_16x16x32_bf16(ah[kt], whi[kt], acc0, 0, 0, 0);
      accb = __builtin_amdgcn_mfma_f32_16x16x32_bf16(ah[kt], wlo[kt], accb, 0, 0, 0);
      accc = __builtin_amdgcn_mfma_f32_16x16x32_bf16(al[kt], whi[kt], accc, 0, 0, 0);
    }
    #pragma unroll
    for (int reg = 0; reg < 4; ++reg) {  // all 4 D-rows are real
      float v = tanh_fast(acc0[reg] + accb[reg] + accc[reg]);
      unsigned short p = bf16_rne(v);
      wh[wo[reg]] = (short)p;
      wl[wo[reg]] = (short)bf16_rne(v - bf16_f(p));
    }
  };

  __syncthreads();

  // ======================= encoder: 64 steps, unrolled x2 =======================
  for (int t = 0; t < TSTEPS; t += 2) {
    {
      short8 ah[4], al[4];
      load_frags(h_hi0, h_lo0, ah, al);
      f32x4 a;
      #pragma unroll
      for (int reg = 0; reg < 4; ++reg) {
        const f32x4 xv = *(const f32x4*)&x_lds[xb[reg] + t * 4];
        a[reg] = bias + wi[0] * xv[0] + wi[1] * xv[1] + wi[2] * xv[2];
      }
      rnn_core(ah, al, a, h_hi1, h_lo1);
    }
    __syncthreads();
    {
      short8 ah[4], al[4];
      load_frags(h_hi1, h_lo1, ah, al);
      f32x4 a;
      #pragma unroll
      for (int reg = 0; reg < 4; ++reg) {
        const f32x4 xv = *(const f32x4*)&x_lds[xb[reg] + (t + 1) * 4];
        a[reg] = bias + wi[0] * xv[0] + wi[1] * xv[1] + wi[2] * xv[2];
      }
      rnn_core(ah, al, a, h_hi0, h_lo0);
    }
    __syncthreads();
  }
  // h_enc now in h_hi0/h_lo0.

  // ======================= decoder setup =======================
  #pragma unroll
  for (int kt = 0; kt < 4; ++kt) {
    const float* p = dWhh + jj * H + kt * 32 + l4 * 8;
    split_frag(*(const f32x4*)p, *(const f32x4*)(p + 4), whi[kt], wlo[kt]);
  }
  bias = dbih[jj] + dbhh[jj];
  #pragma unroll
  for (int i = 0; i < 3; ++i) wi[i] = dWih[jj * 3 + i];

  // fc head as MFMA B-fragments: B[k][n=o] = fcW[o][k], lanes ln>=3 zero.
  short8 fhi[4];
  #pragma unroll
  for (int kt = 0; kt < 4; ++kt) {
    f32x4 a = {0.f, 0.f, 0.f, 0.f}, b = {0.f, 0.f, 0.f, 0.f};
    if (ln < 3) {
      const float* p = fcW + ln * H + kt * 32 + l4 * 8;
      a = *(const f32x4*)p;
      b = *(const f32x4*)(p + 4);
    }
    short8 hi;
    #pragma unroll
    for (int e = 0; e < 4; ++e) {
      hi[e] = (short)bf16_rne(a[e]);
      hi[e + 4] = (short)bf16_rne(b[e]);
    }
    fhi[kt] = hi;
  }
  const float fcbl = (ln < 3) ? fcb[ln] : 0.f;

  if (tid < 48) {
    int r = tid / 3, i = tid - 3 * (tid / 3);
    inp_lds[r][i] = x_lds[r * XSTRIDE + 63 * 4 + i];   // dec_in0 = x[:, -1, :]
  }
  __syncthreads();

  // ---- decoder step 0 (raw dWhh + real input) ----
  {
    short8 ah[4], al[4];
    load_frags(h_hi0, h_lo0, ah, al);
    f32x4 a;
    #pragma unroll
    for (int reg = 0; reg < 4; ++reg) {
      const int r = l4 * 4 + reg;
      a[reg] = bias + wi[0] * inp_lds[r][0] + wi[1] * inp_lds[r][1]
                    + wi[2] * inp_lds[r][2];
    }
    rnn_core(ah, al, a, h_hi1, h_lo1);
  }
  __syncthreads();

  // ---- fold feedback: W' = dWhh + dWih@fcW ; bias' = bias + dWih@fcb ----
  #pragma unroll
  for (int kt = 0; kt < 4; ++kt) {
    const int kb = kt * 32 + l4 * 8;
    f32x4 a = *(const f32x4*)(dWhh + jj * H + kb);
    f32x4 b = *(const f32x4*)(dWhh + jj * H + kb + 4);
    #pragma unroll
    for (int o = 0; o < 3; ++o) {
      const f32x4 fa = *(const f32x4*)(fcW + o * H + kb);
      const f32x4 fb = *(const f32x4*)(fcW + o * H + kb + 4);
      #pragma unroll
      for (int e = 0; e < 4; ++e) {
        a[e] += wi[o] * fa[e];
        b[e] += wi[o] * fb[e];
      }
    }
    split_frag(a, b, whi[kt], wlo[kt]);
  }
  const float biasp = bias + wi[0] * fcb[0] + wi[1] * fcb[1] + wi[2] * fcb[2];
  const f32x4 accd = {biasp, biasp, biasp, biasp};

  // ======================= decoder steps 1..31: 1 barrier/step =======================
  const short* rdh = h_hi1; const short* rdl = h_lo1;
  short* wrh = h_hi0;       short* wrl = h_lo0;
  for (int s = 1; s < PRED; ++s) {
    short8 ah[4], al[4];
    load_frags(rdh, rdl, ah, al);
    rnn_core(ah, al, accd, wrh, wrl);
    // pred[s-1] = fcW·h[s-1] + fcb via MFMA on one rotating wave (off-path)
    if (w == (s & 7)) {
      f32x4 f0 = {0.f, 0.f, 0.f, 0.f};
      f32x4 f1 = {0.f, 0.f, 0.f, 0.f};
      #pragma unroll
      for (int kt = 0; kt < 4; ++kt) {
        f0 = __builtin_amdgcn_mfma_f32_16x16x32_bf16(ah[kt], fhi[kt], f0, 0, 0, 0);
        f1 = __builtin_amdgcn_mfma_f32_16x16x32_bf16(al[kt], fhi[kt], f1, 0, 0, 0);
      }
      if (ln < 3) {
        #pragma unroll
        for (int reg = 0; reg < 4; ++reg)
          out[((size_t)(r0 + l4 * 4 + reg) * PRED + (s - 1)) * 3 + ln] =
              f0[reg] + f1[reg] + fcbl;
      }
    }
    __syncthreads();
    const short* th = rdh; rdh = wrh; wrh = (short*)th;
    const short* tl = rdl; rdl = wrl; wrl = (short*)tl;
  }
  // ---- drain: pred[31] from final h ----
  if (w == 0) {
    short8 ah[4], al[4];
    load_frags(rdh, rdl, ah, al);
    f32x4 f0 = {0.f, 0.f, 0.f, 0.f};
    f32x4 f1 = {0.f, 0.f, 0.f, 0.f};
    #pragma unroll
    for (int kt = 0; kt < 4; ++kt) {
      f0 = __builtin_amdgcn_mfma_f32_16x16x32_bf16(ah[kt], fhi[kt], f0, 0, 0, 0);
      f1 = __builtin_amdgcn_mfma_f32_16x16x32_bf16(al[kt], fhi[kt], f1, 0, 0, 0);
    }
    if (ln < 3) {
      #pragma unroll
      for (int reg = 0; reg < 4; ++reg)
        out[((size_t)(r0 + l4 * 4 + reg) * PRED + (PRED - 1)) * 3 + ln] =
            f0[reg] + f1[reg] + fcbl;
    }
  }
}

extern "C" void kernel_launch(void* const* d_in, const int* in_sizes, int n_in,
                              void* d_out, int out_size, void* d_ws, size_t ws_size,
                              hipStream_t stream) {
  (void)in_sizes; (void)n_in; (void)out_size; (void)d_ws; (void)ws_size;
  const float* x    = (const float*)d_in[0];
  const float* eWih = (const float*)d_in[1];
  const float* eWhh = (const float*)d_in[2];
  const float* ebih = (const float*)d_in[3];
  const float* ebhh = (const float*)d_in[4];
  const float* dWih = (const float*)d_in[5];
  const float* dWhh = (const float*)d_in[6];
  const float* dbih = (const float*)d_in[7];
  const float* dbhh = (const float*)d_in[8];
  const float* fcW  = (const float*)d_in[9];
  const float* fcb  = (const float*)d_in[10];
  float* out = (float*)d_out;
  traj_kernel<<<dim3(256), dim3(512), 0, stream>>>(
      x, eWih, eWhh, ebih, ebhh, dWih, dWhh, dbih, dbhh, fcW, fcb, out);
}